// Round 1
// 646.808 us; speedup vs baseline: 1.0770x; 1.0770x over previous
//
#include <hip/hip_runtime.h>
#include <hip/hip_bf16.h>

typedef __bf16 bf16;
typedef bf16 bf16x8 __attribute__((ext_vector_type(8)));
typedef bf16 bf16x4 __attribute__((ext_vector_type(4)));
typedef float f32x4 __attribute__((ext_vector_type(4)));

#define HID 1024
#define FFD 2048

typedef __attribute__((address_space(3))) void lds_void;
typedef const __attribute__((address_space(1))) void gm_void;

__device__ __forceinline__ void gload_lds16(const bf16* g, bf16* l)
{
    __builtin_amdgcn_global_load_lds((gm_void*)g, (lds_void*)l, 16, 0, 0);
}

// ---------------------------------------------------------------------------
// fused fp32->bf16 transpose: in fp32 (R,C) -> out bf16 (C,R). R,C % 32 == 0.
// ---------------------------------------------------------------------------
__global__ __launch_bounds__(256) void cvt_t_bf16_kernel(
    const float* __restrict__ in, bf16* __restrict__ out, int R, int C)
{
    __shared__ bf16 tile[32][33];
    const int c0 = blockIdx.x * 32, r0 = blockIdx.y * 32;
    const int tx = threadIdx.x & 31, ty = threadIdx.x >> 5;
#pragma unroll
    for (int i = ty; i < 32; i += 8)
        tile[i][tx] = (bf16)in[(long)(r0 + i) * C + c0 + tx];
    __syncthreads();
#pragma unroll
    for (int i = ty; i < 32; i += 8)
        out[(long)(c0 + i) * R + r0 + tx] = tile[tx][i];
}

// ---------------------------------------------------------------------------
// bf16 GEMM: C(M,N) = A(M,K) @ Bt(N,K)^T + bias. 1D grid, XCD-swizzled.
// m97-style unpadded [128][32] LDS + async global_load_lds (16B).
// Optional device-side row count (cntp): tiles past *cntp exit early.
// ---------------------------------------------------------------------------
template <int ACT, int OUTBF16>
__global__ __launch_bounds__(256) void gemm_bf16_kernel(
    const bf16* __restrict__ A, const bf16* __restrict__ B,
    const float* __restrict__ bias, void* __restrict__ Cp,
    int M, int N, int K, int NB, const int* __restrict__ cntp)
{
    const int total = gridDim.x;
    const int h = blockIdx.x;
    const int t = (total % 8 == 0) ? ((h & 7) * (total >> 3) + (h >> 3)) : h;
    const int bn = t % NB, bm = t / NB;

    int Meff = M;
    if (cntp) Meff = *cntp;
    if (bm * 128 >= Meff) return;

    const int tid  = threadIdx.x;
    const int lane = tid & 63, wave = tid >> 6;
    const int wr   = wave >> 1, wc = wave & 1;

    __shared__ bf16 As[128][32];
    __shared__ bf16 Bs[128][32];

    f32x4 acc[4][4] = {};

    const int srow = wave * 16 + (lane >> 2);
    const int scol = (lane & 3) << 3;
    const long ga0 = (long)min(bm * 128 + srow,      Meff - 1) * K + scol;
    const long ga1 = (long)min(bm * 128 + srow + 64, Meff - 1) * K + scol;
    const long gb0 = (long)(bn * 128 + srow)      * K + scol;
    const long gb1 = (long)(bn * 128 + srow + 64) * K + scol;
    bf16* ldsA0 = &As[0][0] + wave * 512;
    bf16* ldsA1 = &As[0][0] + 2048 + wave * 512;
    bf16* ldsB0 = &Bs[0][0] + wave * 512;
    bf16* ldsB1 = &Bs[0][0] + 2048 + wave * 512;

    const int quad = lane >> 4;
    const int mr   = lane & 15;
    const int kf   = quad * 8;

    for (int k0 = 0; k0 < K; k0 += 32) {
        gload_lds16(A + ga0 + k0, ldsA0);
        gload_lds16(A + ga1 + k0, ldsA1);
        gload_lds16(B + gb0 + k0, ldsB0);
        gload_lds16(B + gb1 + k0, ldsB1);
        __syncthreads();

        bf16x8 af[4], bfr[4];
#pragma unroll
        for (int i = 0; i < 4; ++i) af[i]  = *(const bf16x8*)&As[wr * 64 + i * 16 + mr][kf];
#pragma unroll
        for (int j = 0; j < 4; ++j) bfr[j] = *(const bf16x8*)&Bs[wc * 64 + j * 16 + mr][kf];
#pragma unroll
        for (int i = 0; i < 4; ++i)
#pragma unroll
            for (int j = 0; j < 4; ++j)
                acc[i][j] = __builtin_amdgcn_mfma_f32_16x16x32_bf16(af[i], bfr[j], acc[i][j], 0, 0, 0);
        __syncthreads();
    }

    const int crow = quad * 4;
#pragma unroll
    for (int i = 0; i < 4; ++i) {
#pragma unroll
        for (int j = 0; j < 4; ++j) {
            const int   col = bn * 128 + wc * 64 + j * 16 + mr;
            const float bv  = bias[col];
#pragma unroll
            for (int r = 0; r < 4; ++r) {
                const int row = bm * 128 + wr * 64 + i * 16 + crow + r;
                if (row < Meff) {
                    float v = acc[i][j][r] + bv;
                    if (ACT == 1) v = fmaxf(v, 0.f);
                    if (OUTBF16) ((bf16*)Cp)[(long)row * N + col] = (bf16)v;
                    else         ((float*)Cp)[(long)row * N + col] = v;
                }
            }
        }
    }
}

// ---------------------------------------------------------------------------
// Split-K fp32-input GEMM (transformer, small M): partials to `part`.
// ---------------------------------------------------------------------------
template <int KS>
__global__ __launch_bounds__(256) void gemm_sk_kernel(
    const float* __restrict__ A, const float* __restrict__ Bt,
    float* __restrict__ part, int M, int N, int K)
{
    const int tid  = threadIdx.x;
    const int bn   = blockIdx.x, bm = blockIdx.y, kz = blockIdx.z;
    const int lane = tid & 63, wave = tid >> 6;
    const int wr   = wave >> 1, wc = wave & 1;

    __shared__ bf16 As[128][40];
    __shared__ bf16 Bs[128][40];

    f32x4 acc[4][4] = {};

    const int  lr = tid >> 2;
    const int  lc = (tid & 3) << 3;
    const long a0 = (long)min(bm * 128 + lr,      M - 1) * K;
    const long a1 = (long)min(bm * 128 + lr + 64, M - 1) * K;
    const long b0 = (long)(bn * 128 + lr)      * K;
    const long b1 = (long)(bn * 128 + lr + 64) * K;

    const int quad = lane >> 4;
    const int mr   = lane & 15;
    const int kf   = quad * 8;

    const int Kc   = K / KS;
    const int kbeg = kz * Kc, kend = kbeg + Kc;

    float4 ra[4], rb[4];
    auto load_chunk = [&](int k0) {
        ra[0] = *(const float4*)&A[a0 + k0 + lc];
        ra[1] = *(const float4*)&A[a0 + k0 + lc + 4];
        ra[2] = *(const float4*)&A[a1 + k0 + lc];
        ra[3] = *(const float4*)&A[a1 + k0 + lc + 4];
        rb[0] = *(const float4*)&Bt[b0 + k0 + lc];
        rb[1] = *(const float4*)&Bt[b0 + k0 + lc + 4];
        rb[2] = *(const float4*)&Bt[b1 + k0 + lc];
        rb[3] = *(const float4*)&Bt[b1 + k0 + lc + 4];
    };

    load_chunk(kbeg);
    for (int k0 = kbeg; k0 < kend; k0 += 32) {
        {
            bf16x8 v0 = {(bf16)ra[0].x,(bf16)ra[0].y,(bf16)ra[0].z,(bf16)ra[0].w,
                         (bf16)ra[1].x,(bf16)ra[1].y,(bf16)ra[1].z,(bf16)ra[1].w};
            *(bf16x8*)&As[lr][lc] = v0;
            bf16x8 v1 = {(bf16)ra[2].x,(bf16)ra[2].y,(bf16)ra[2].z,(bf16)ra[2].w,
                         (bf16)ra[3].x,(bf16)ra[3].y,(bf16)ra[3].z,(bf16)ra[3].w};
            *(bf16x8*)&As[lr + 64][lc] = v1;
            bf16x8 v2 = {(bf16)rb[0].x,(bf16)rb[0].y,(bf16)rb[0].z,(bf16)rb[0].w,
                         (bf16)rb[1].x,(bf16)rb[1].y,(bf16)rb[1].z,(bf16)rb[1].w};
            *(bf16x8*)&Bs[lr][lc] = v2;
            bf16x8 v3 = {(bf16)rb[2].x,(bf16)rb[2].y,(bf16)rb[2].z,(bf16)rb[2].w,
                         (bf16)rb[3].x,(bf16)rb[3].y,(bf16)rb[3].z,(bf16)rb[3].w};
            *(bf16x8*)&Bs[lr + 64][lc] = v3;
        }
        __syncthreads();
        if (k0 + 32 < kend) load_chunk(k0 + 32);

        bf16x8 af[4], bfr[4];
#pragma unroll
        for (int i = 0; i < 4; ++i) af[i]  = *(const bf16x8*)&As[wr * 64 + i * 16 + mr][kf];
#pragma unroll
        for (int j = 0; j < 4; ++j) bfr[j] = *(const bf16x8*)&Bs[wc * 64 + j * 16 + mr][kf];
#pragma unroll
        for (int i = 0; i < 4; ++i)
#pragma unroll
            for (int j = 0; j < 4; ++j)
                acc[i][j] = __builtin_amdgcn_mfma_f32_16x16x32_bf16(af[i], bfr[j], acc[i][j], 0, 0, 0);
        __syncthreads();
    }

    const int crow = quad * 4;
    float* dst = part + (size_t)kz * M * N;
#pragma unroll
    for (int i = 0; i < 4; ++i) {
#pragma unroll
        for (int j = 0; j < 4; ++j) {
            const int col = bn * 128 + wc * 64 + j * 16 + mr;
#pragma unroll
            for (int r = 0; r < 4; ++r) {
                const int row = bm * 128 + wr * 64 + i * 16 + crow + r;
                if (row < M) dst[(long)row * N + col] = acc[i][j][r];
            }
        }
    }
}

// reduce KS partials + bias (+relu) -> C
template <int ACT, int KS>
__global__ __launch_bounds__(256) void sk_reduce_kernel(
    const float* __restrict__ part, const float* __restrict__ bias,
    float* __restrict__ C, long MN, int N)
{
    long i = ((long)blockIdx.x * 256 + threadIdx.x) * 4;
    if (i >= MN) return;
    float4 s = *(const float4*)&part[i];
#pragma unroll
    for (int k = 1; k < KS; ++k) {
        float4 p = *(const float4*)&part[(size_t)k * MN + i];
        s.x += p.x; s.y += p.y; s.z += p.z; s.w += p.w;
    }
    const int col = (int)(i % N);
    float4 bv = *(const float4*)&bias[col];
    s.x += bv.x; s.y += bv.y; s.z += bv.z; s.w += bv.w;
    if (ACT) {
        s.x = fmaxf(s.x, 0.f); s.y = fmaxf(s.y, 0.f);
        s.z = fmaxf(s.z, 0.f); s.w = fmaxf(s.w, 0.f);
    }
    *(float4*)&C[i] = s;
}

// ---------------------------------------------------------------------------
// LayerNorm core (row = 1024, block = 256, 4 ch/thread)
// ---------------------------------------------------------------------------
__device__ __forceinline__ void ln_finish(float v[4], int c0, const float* g,
                                          const float* beta, float* outrow)
{
    float s1 = v[0] + v[1] + v[2] + v[3];
    float s2 = v[0] * v[0] + v[1] * v[1] + v[2] * v[2] + v[3] * v[3];
    __shared__ float red[8];
    for (int o = 32; o; o >>= 1) { s1 += __shfl_down(s1, o); s2 += __shfl_down(s2, o); }
    const int wave = threadIdx.x >> 6, lane = threadIdx.x & 63;
    if (lane == 0) { red[wave] = s1; red[4 + wave] = s2; }
    __syncthreads();
    if (threadIdx.x == 0) {
        red[0] += red[1] + red[2] + red[3];
        red[4] += red[5] + red[6] + red[7];
    }
    __syncthreads();
    const float mean = red[0] * (1.f / HID);
    const float var  = fmaxf(red[4] * (1.f / HID) - mean * mean, 0.f);
    const float rstd = rsqrtf(var + 1e-5f);
#pragma unroll
    for (int k = 0; k < 4; ++k) {
        int c = c0 + k;
        outrow[c] = (v[k] - mean) * rstd * g[c] + beta[c];
    }
}

// fused: reduce KS partials + bias + residual(srcio) -> LN -> srcio (in place)
template <int KS>
__global__ __launch_bounds__(256) void sk_reduce_ln_kernel(
    const float* __restrict__ part, const float* __restrict__ bias,
    float* __restrict__ srcio, const float* __restrict__ g,
    const float* __restrict__ beta, long MN)
{
    const long row = blockIdx.x;
    const int c0 = threadIdx.x * 4;
    const long base = row * HID + c0;
    float4 s = *(const float4*)&part[base];
#pragma unroll
    for (int k = 1; k < KS; ++k) {
        float4 p = *(const float4*)&part[(size_t)k * MN + base];
        s.x += p.x; s.y += p.y; s.z += p.z; s.w += p.w;
    }
    float4 bv = *(const float4*)&bias[c0];
    float4 rv = *(const float4*)&srcio[base];
    float v[4] = {s.x + bv.x + rv.x, s.y + bv.y + rv.y,
                  s.z + bv.z + rv.z, s.w + bv.w + rv.w};
    ln_finish(v, c0, g, beta, srcio + row * HID);
}

// ---------------------------------------------------------------------------
// CSR build
// ---------------------------------------------------------------------------
__global__ void zero_i32_kernel(int* __restrict__ p, int n)
{
    int i = blockIdx.x * 256 + threadIdx.x;
    if (i < n) p[i] = 0;
}

__global__ void hist_kernel(const int* __restrict__ ei, int E, int* __restrict__ deg)
{
    int e = blockIdx.x * 256 + threadIdx.x;
    if (e < E) atomicAdd(&deg[ei[e]], 1);
}

__global__ void scan_kernel(const int* __restrict__ deg, int* __restrict__ rowstart,
                            int* __restrict__ cursor, int n)
{
    __shared__ int sm[1024];
    __shared__ int carry;
    if (threadIdx.x == 0) carry = 0;
    __syncthreads();
    for (int base = 0; base < n; base += 1024) {
        int i = base + threadIdx.x;
        int v = (i < n) ? deg[i] : 0;
        sm[threadIdx.x] = v;
        __syncthreads();
        for (int off = 1; off < 1024; off <<= 1) {
            int t = (threadIdx.x >= off) ? sm[threadIdx.x - off] : 0;
            __syncthreads();
            sm[threadIdx.x] += t;
            __syncthreads();
        }
        if (i < n) { int ex = carry + sm[threadIdx.x] - v; rowstart[i] = ex; cursor[i] = ex; }
        __syncthreads();
        if (threadIdx.x == 0) carry += sm[1023];
        __syncthreads();
    }
    if (threadIdx.x == 0) rowstart[n] = carry;
}

__global__ void scatter_kernel(const int* __restrict__ ei, int E,
                               int* __restrict__ cursor, int* __restrict__ eidx)
{
    int e = blockIdx.x * 256 + threadIdx.x;
    if (e < E) { int p = atomicAdd(&cursor[ei[e]], 1); eidx[p] = e; }
}

// ---------------------------------------------------------------------------
// Frontier construction: only L target rows of GAT2 output are consumed
// downstream, so GAT runs on the 2-hop neighborhood of target_idx only.
// ---------------------------------------------------------------------------
// mark sources of edges into the L target nodes (wave per target)
__global__ __launch_bounds__(256) void frontier0_kernel(
    const int* __restrict__ target_idx, int L, const int* __restrict__ rowstart,
    const int* __restrict__ eidx, const int* __restrict__ ei, int E,
    int* __restrict__ f1)
{
    const int wave = threadIdx.x >> 6, lane = threadIdx.x & 63;
    const int w = blockIdx.x * 4 + wave;
    if (w >= L) return;
    const int n = target_idx[w];
    if (lane == 0) f1[n] = 1;
    const int rs = rowstart[n];
    int deg = rowstart[n + 1] - rs;
    if (deg > 128) deg = 128;
    for (int j = lane; j < deg; j += 64)
        f1[ei[E + eidx[rs + j]]] = 1;
}

// mark sources of edges into the cnt1 frontier-1 nodes (wave per node)
__global__ __launch_bounds__(256) void frontier1_kernel(
    const int* __restrict__ list1, const int* __restrict__ cnt1p,
    const int* __restrict__ rowstart, const int* __restrict__ eidx,
    const int* __restrict__ ei, int E, int* __restrict__ f2)
{
    const int wave = threadIdx.x >> 6, lane = threadIdx.x & 63;
    const int w = blockIdx.x * 4 + wave;
    if (w >= *cnt1p) return;
    const int n = list1[w];
    if (lane == 0) f2[n] = 1;
    const int rs = rowstart[n];
    int deg = rowstart[n + 1] - rs;
    if (deg > 128) deg = 128;
    for (int j = lane; j < deg; j += 64)
        f2[ei[E + eidx[rs + j]]] = 1;
}

// flags -> compact list + node->compact map (order nondeterministic, consistent)
__global__ __launch_bounds__(256) void compact_kernel(
    const int* __restrict__ flags, int* __restrict__ map, int* __restrict__ list,
    int* __restrict__ cnt, int n)
{
    int i = blockIdx.x * 256 + threadIdx.x;
    if (i < n && flags[i]) {
        int p = atomicAdd(cnt, 1);
        list[p] = i;
        map[i] = p;
    }
}

// gather fp32 rows by list, convert to bf16 compact rows (block per row)
__global__ __launch_bounds__(256) void gather_cvt_kernel(
    const float* __restrict__ src, bf16* __restrict__ dst,
    const int* __restrict__ list, const int* __restrict__ cntp, int C)
{
    const int r = blockIdx.x;
    if (r >= *cntp) return;
    const long i = (long)list[r] * C;
    const long o = (long)r * C;
    for (int c = threadIdx.x * 4; c < C; c += 1024) {
        float4 f = *(const float4*)&src[i + c];
        bf16x4 v = {(bf16)f.x, (bf16)f.y, (bf16)f.z, (bf16)f.w};
        *(bf16x4*)&dst[o + c] = v;
    }
}

// ---------------------------------------------------------------------------
// Wave-per-node GATv2 over a compact node list with src remapping.
// Lane l owns ch [l*16, l*16+16). NH=4: head = lane>>4, reduce over 16 lanes.
// deg <= 128 (dataset max ~40; self-loops guarantee deg >= 1).
// Output row = w (compact). xr row = XRMAP ? srcmap[n] : w.
// ---------------------------------------------------------------------------
template <int NH, int LRELU, int OUTBF16, int XRMAP>
__global__ __launch_bounds__(256) void gat_wave_idx_kernel(
    const bf16* __restrict__ xl, const bf16* __restrict__ xr,
    const float* __restrict__ att,
    const int* __restrict__ ei, const int* __restrict__ rowstart,
    const int* __restrict__ eidx, const int* __restrict__ srcmap,
    const int* __restrict__ nodelist, const int* __restrict__ cntp, int Nhost,
    const float* __restrict__ bias, void* __restrict__ outp, int E)
{
    const int wave = threadIdx.x >> 6, lane = threadIdx.x & 63;
    const int w = blockIdx.x * 4 + wave;
    const int cnt = cntp ? *cntp : Nhost;
    if (w >= cnt) return;
    const int n = nodelist[w];

    const int rs = rowstart[n];
    int deg = rowstart[n + 1] - rs;
    if (deg > 128) deg = 128;

    // compact src indices for up to 128 edges live in 2 registers/lane
    int my_src = srcmap[ei[E + eidx[min(rs + lane, E - 1)]]];
    int my_src2 = 0;
    if (deg > 64) my_src2 = srcmap[ei[E + eidx[min(rs + 64 + lane, E - 1)]]];

    const int xrrow = XRMAP ? srcmap[n] : w;
    const int c0 = lane * 16;
    float xrf[16], av[16];
    {
        bf16x8 r0 = *(const bf16x8*)&xr[(long)xrrow * HID + c0];
        bf16x8 r1 = *(const bf16x8*)&xr[(long)xrrow * HID + c0 + 8];
#pragma unroll
        for (int t = 0; t < 8; ++t) { xrf[t] = (float)r0[t]; xrf[8 + t] = (float)r1[t]; }
        float4 t0 = *(const float4*)&att[c0],     t1 = *(const float4*)&att[c0 + 4];
        float4 t2 = *(const float4*)&att[c0 + 8], t3 = *(const float4*)&att[c0 + 12];
        av[0]=t0.x; av[1]=t0.y; av[2]=t0.z;  av[3]=t0.w;
        av[4]=t1.x; av[5]=t1.y; av[6]=t1.z;  av[7]=t1.w;
        av[8]=t2.x; av[9]=t2.y; av[10]=t2.z; av[11]=t2.w;
        av[12]=t3.x; av[13]=t3.y; av[14]=t3.z; av[15]=t3.w;
    }

    float m = -1e30f, s = 0.f;
    float acc[16];
#pragma unroll
    for (int t = 0; t < 16; ++t) acc[t] = 0.f;

    // prefetch edge 0's row chunk
    int sj = __shfl(my_src, 0);
    bf16x8 na0 = *(const bf16x8*)&xl[(long)sj * HID + c0];
    bf16x8 na1 = *(const bf16x8*)&xl[(long)sj * HID + c0 + 8];

    for (int j = 0; j < deg; ++j) {
        bf16x8 x0 = na0, x1 = na1;
        if (j + 1 < deg) {
            int msrc = (j + 1 < 64) ? my_src : my_src2;
            int sn = __shfl(msrc, (j + 1) & 63);
            na0 = *(const bf16x8*)&xl[(long)sn * HID + c0];
            na1 = *(const bf16x8*)&xl[(long)sn * HID + c0 + 8];
        }
        float xf[16];
#pragma unroll
        for (int t = 0; t < 8; ++t) { xf[t] = (float)x0[t]; xf[8 + t] = (float)x1[t]; }
        float partial = 0.f;
#pragma unroll
        for (int t = 0; t < 16; ++t) {
            float v = xf[t] + xrf[t];
            v = v > 0.f ? v : 0.2f * v;
            partial += v * av[t];
        }
        const int RW = (NH == 4) ? 16 : 64;
#pragma unroll
        for (int o = 1; o < RW; o <<= 1) partial += __shfl_xor(partial, o);
        // online softmax update
        float mn = fmaxf(m, partial);
        float f = __expf(m - mn);
        float p = __expf(partial - mn);
        s = s * f + p;
#pragma unroll
        for (int t = 0; t < 16; ++t) acc[t] = acc[t] * f + p * xf[t];
        m = mn;
    }

    const float dinv = 1.f / (s + 1e-16f);
    float bv[16];
    {
        float4 t0 = *(const float4*)&bias[c0],     t1 = *(const float4*)&bias[c0 + 4];
        float4 t2 = *(const float4*)&bias[c0 + 8], t3 = *(const float4*)&bias[c0 + 12];
        bv[0]=t0.x; bv[1]=t0.y; bv[2]=t0.z;  bv[3]=t0.w;
        bv[4]=t1.x; bv[5]=t1.y; bv[6]=t1.z;  bv[7]=t1.w;
        bv[8]=t2.x; bv[9]=t2.y; bv[10]=t2.z; bv[11]=t2.w;
        bv[12]=t3.x; bv[13]=t3.y; bv[14]=t3.z; bv[15]=t3.w;
    }
    float ov[16];
#pragma unroll
    for (int t = 0; t < 16; ++t) {
        float v = acc[t] * dinv + bv[t];
        if (LRELU) v = v > 0.f ? v : 0.2f * v;
        ov[t] = v;
    }
    if (OUTBF16) {
        bf16x8 w0, w1;
#pragma unroll
        for (int t = 0; t < 8; ++t) { w0[t] = (bf16)ov[t]; w1[t] = (bf16)ov[8 + t]; }
        *(bf16x8*)&((bf16*)outp)[(long)w * HID + c0] = w0;
        *(bf16x8*)&((bf16*)outp)[(long)w * HID + c0 + 8] = w1;
    } else {
        float* op = (float*)outp + (long)w * HID + c0;
#pragma unroll
        for (int t = 0; t < 4; ++t) {
            float4 wv = {ov[t * 4], ov[t * 4 + 1], ov[t * 4 + 2], ov[t * 4 + 3]};
            *(float4*)&op[t * 4] = wv;
        }
    }
}

// ---------------------------------------------------------------------------
// LayerNorm after cross-attn: x2c row l (compact, per target) + attnb row b
// ---------------------------------------------------------------------------
__global__ __launch_bounds__(256) void ln_cross_kernel(
    const float* __restrict__ x2c, const float* __restrict__ attnb,
    const float* __restrict__ g, const float* __restrict__ beta,
    float* __restrict__ out, int L)
{
    const int row = blockIdx.x;
    const int b = row / L, l = row - b * L;
    const long tr = (long)l * HID, ar = (long)b * HID;
    const int c0 = threadIdx.x * 4;
    float v[4];
#pragma unroll
    for (int k = 0; k < 4; ++k)
        v[k] = x2c[tr + c0 + k] + attnb[ar + c0 + k];
    ln_finish(v, c0, g, beta, out + (long)row * HID);
}

// ---------------------------------------------------------------------------
// Self-attention core: one block per (batch, head). L <= 16, hd = 256.
// ---------------------------------------------------------------------------
__global__ __launch_bounds__(256) void self_attn_kernel(
    const float* __restrict__ qkv, float* __restrict__ out, int L)
{
    const int b = blockIdx.x >> 2, h = blockIdx.x & 3;
    const int tid = threadIdx.x;
    __shared__ float q[16][256], kk[16][256], vv[16][256];
    __shared__ float sc[16][16];
    for (int i = tid; i < L * 256; i += 256) {
        const int l = i >> 8, d = i & 255;
        const long rb = (long)(b * L + l) * 3072 + h * 256 + d;
        q[l][d]  = qkv[rb];
        kk[l][d] = qkv[rb + 1024];
        vv[l][d] = qkv[rb + 2048];
    }
    __syncthreads();
    if (tid < L * L) {
        const int l1 = tid / L, l2 = tid - l1 * L;
        float s = 0.f;
        for (int d = 0; d < 256; ++d) s += q[l1][d] * kk[l2][d];
        sc[l1][l2] = s * 0.0625f;
    }
    __syncthreads();
    if (tid < L) {
        float mx = -1e30f;
        for (int j = 0; j < L; ++j) mx = fmaxf(mx, sc[tid][j]);
        float ssum = 0.f;
        for (int j = 0; j < L; ++j) { float e = expf(sc[tid][j] - mx); sc[tid][j] = e; ssum += e; }
        const float inv = 1.f / ssum;
        for (int j = 0; j < L; ++j) sc[tid][j] *= inv;
    }
    __syncthreads();
    for (int l1 = 0; l1 < L; ++l1) {
        float a = 0.f;
        for (int l2 = 0; l2 < L; ++l2) a += sc[l1][l2] * vv[l2][tid];
        out[(long)(b * L + l1) * HID + h * 256 + tid] = a;
    }
}

// ---------------------------------------------------------------------------
__global__ __launch_bounds__(256) void cls_kernel(
    const float* __restrict__ src, const float* __restrict__ w,
    const float* __restrict__ b, float* __restrict__ out, int rows)
{
    const int row = blockIdx.x * 4 + (threadIdx.x >> 6);
    const int lane = threadIdx.x & 63;
    if (row >= rows) return;
    float s = 0.f;
    for (int c = lane; c < HID; c += 64) s += src[(long)row * HID + c] * w[c];
    for (int o = 32; o; o >>= 1) s += __shfl_down(s, o);
    if (lane == 0) out[row] = s + b[0];
}

// ---------------------------------------------------------------------------
extern "C" void kernel_launch(void* const* d_in, const int* in_sizes, int n_in,
                              void* d_out, int out_size, void* d_ws, size_t ws_size,
                              hipStream_t stream)
{
    const float* img_feat      = (const float*)d_in[0];
    const float* node_features = (const float*)d_in[1];
    const int*   edge_index    = (const int*)d_in[2];
    const int*   target_idx    = (const int*)d_in[3];
    const float* gat1_wl  = (const float*)d_in[4];
    const float* gat1_bl  = (const float*)d_in[5];
    const float* gat1_wr  = (const float*)d_in[6];
    const float* gat1_br  = (const float*)d_in[7];
    const float* gat1_att = (const float*)d_in[8];
    const float* gat1_bias= (const float*)d_in[9];
    const float* gat2_wl  = (const float*)d_in[10];
    const float* gat2_bl  = (const float*)d_in[11];
    const float* gat2_wr  = (const float*)d_in[12];
    const float* gat2_br  = (const float*)d_in[13];
    const float* gat2_att = (const float*)d_in[14];
    const float* gat2_bias= (const float*)d_in[15];
    const float* xa_in_w  = (const float*)d_in[16];
    const float* xa_in_b  = (const float*)d_in[17];
    const float* xa_out_w = (const float*)d_in[18];
    const float* xa_out_b = (const float*)d_in[19];
    const float* xl_l1_w  = (const float*)d_in[20];
    const float* xl_l1_b  = (const float*)d_in[21];
    const float* xl_l2_w  = (const float*)d_in[22];
    const float* xl_l2_b  = (const float*)d_in[23];
    const float* xl_n1_g  = (const float*)d_in[24];
    const float* xl_n1_b  = (const float*)d_in[25];
    const float* xl_n2_g  = (const float*)d_in[26];
    const float* xl_n2_b  = (const float*)d_in[27];
    const float* enc_in_w = (const float*)d_in[28];
    const float* enc_in_b = (const float*)d_in[29];
    const float* enc_out_w= (const float*)d_in[30];
    const float* enc_out_b= (const float*)d_in[31];
    const float* enc_l1_w = (const float*)d_in[32];
    const float* enc_l1_b = (const float*)d_in[33];
    const float* enc_l2_w = (const float*)d_in[34];
    const float* enc_l2_b = (const float*)d_in[35];
    const float* enc_n1_g = (const float*)d_in[36];
    const float* enc_n1_b = (const float*)d_in[37];
    const float* enc_n2_g = (const float*)d_in[38];
    const float* enc_n2_b = (const float*)d_in[39];
    const float* cls_w    = (const float*)d_in[40];
    const float* cls_b    = (const float*)d_in[41];

    const int DF = in_sizes[4] / HID;          // 768
    const int Nn = in_sizes[1] / DF;           // 8000
    const int E  = in_sizes[2] / 2;            // 104000
    const int L  = in_sizes[3];                // 14
    const int B  = in_sizes[0] / HID;          // 32
    const int R  = B * L;                      // 448

    // frontier caps (worst case; deg capped at 128 everywhere consistently)
    const int cap1 = ((L * 129 + 127) / 128) * 128;   // 1-hop nodes (1920 for L=14)

    // ---- workspace layout ----
    char* basep = (char*)d_ws;
    size_t off = 0;
    auto alloc = [&](size_t bytes) -> char* {
        char* r = basep + off; off += (bytes + 255) & ~(size_t)255; return r;
    };

    bf16* w1lT = (bf16*)alloc((size_t)DF * HID * 2);
    bf16* w1rT = (bf16*)alloc((size_t)DF * HID * 2);
    bf16* w2lT = (bf16*)alloc((size_t)HID * HID * 2);
    bf16* w2rT = (bf16*)alloc((size_t)HID * HID * 2);

    int*   deg      = (int*)alloc((size_t)Nn * 4);
    int*   rowstart = (int*)alloc((size_t)(Nn + 1) * 4);
    int*   cursor   = (int*)alloc((size_t)(Nn + 1) * 4);
    int*   eidx     = (int*)alloc((size_t)E * 4);

    int*   fbuf = (int*)alloc((size_t)(2 * Nn + 8) * 4);  // f1 | f2 | cnt1 | cnt2
    int*   f1 = fbuf, *f2 = fbuf + Nn;
    int*   cnt1 = fbuf + 2 * Nn, *cnt2 = fbuf + 2 * Nn + 1;
    int*   map1  = (int*)alloc((size_t)Nn * 4);
    int*   map2  = (int*)alloc((size_t)Nn * 4);
    int*   list1 = (int*)alloc((size_t)cap1 * 4);
    int*   list2 = (int*)alloc((size_t)Nn * 4);

    bf16* nf1c = (bf16*)alloc((size_t)cap1 * DF * 2);
    bf16* nf2c = (bf16*)alloc((size_t)Nn * DF * 2);
    bf16* xrc  = (bf16*)alloc((size_t)cap1 * HID * 2);
    bf16* xlc  = (bf16*)alloc((size_t)Nn * HID * 2);   // reused for transformer bufs
    bf16* x1c  = (bf16*)alloc((size_t)cap1 * HID * 2);
    bf16* xl2c = (bf16*)alloc((size_t)cap1 * HID * 2);
    bf16* xr2c = (bf16*)alloc((size_t)cap1 * HID * 2);
    float* x2c = (float*)alloc((size_t)L * HID * 4);
    float* skpart = (float*)alloc((size_t)8 * R * 3 * HID * 4);

    // transformer small buffers overlay xlc (dead after GAT1 aggregation)
    {
        char* qb = (char*)xlc; size_t qoff = 0;
        auto alloc2 = [&](size_t bytes) -> char* {
            char* r = qb + qoff; qoff += (bytes + 255) & ~(size_t)255; return r;
        };
        float* vproj  = (float*)alloc2((size_t)B * HID * 4);
        float* attnb  = (float*)alloc2((size_t)B * HID * 4);
        float* srcbuf = (float*)alloc2((size_t)R * HID * 4);
        float* h1buf  = (float*)alloc2((size_t)R * FFD * 4);
        float* ffbuf  = (float*)alloc2((size_t)R * HID * 4);
        float* qkvbuf = (float*)alloc2((size_t)R * 3 * HID * 4);

        const int gE  = (E + 255) / 256;
        const long MNr = (long)R * HID;
        const int gMn2 = (Nn + 127) / 128;     // row tiles for cap2 = Nn
        const int gMn1 = (cap1 + 127) / 128;   // row tiles for cap1

        auto gemm_sk4 = [&](const float* A, const float* Bt, const float* bias,
                            float* C, int M, int N, int K, int act) {
            gemm_sk_kernel<4><<<dim3(N / 128, (M + 127) / 128, 4), 256, 0, stream>>>(
                A, Bt, skpart, M, N, K);
            long MN = (long)M * N;
            int g = (int)((MN / 4 + 255) / 256);
            if (act) sk_reduce_kernel<1,4><<<g, 256, 0, stream>>>(skpart, bias, C, MN, N);
            else     sk_reduce_kernel<0,4><<<g, 256, 0, stream>>>(skpart, bias, C, MN, N);
        };
        auto gemm_sk8 = [&](const float* A, const float* Bt, const float* bias,
                            float* C, int M, int N, int K, int act) {
            gemm_sk_kernel<8><<<dim3(N / 128, (M + 127) / 128, 8), 256, 0, stream>>>(
                A, Bt, skpart, M, N, K);
            long MN = (long)M * N;
            int g = (int)((MN / 4 + 255) / 256);
            if (act) sk_reduce_kernel<1,8><<<g, 256, 0, stream>>>(skpart, bias, C, MN, N);
            else     sk_reduce_kernel<0,8><<<g, 256, 0, stream>>>(skpart, bias, C, MN, N);
        };
        auto gemm_sk8_ln = [&](const float* A, const float* Bt, const float* bias,
                               float* srcio, const float* g, const float* beta, int K) {
            gemm_sk_kernel<8><<<dim3(HID / 128, (R + 127) / 128, 8), 256, 0, stream>>>(
                A, Bt, skpart, R, HID, K);
            sk_reduce_ln_kernel<8><<<R, 256, 0, stream>>>(skpart, bias, srcio, g, beta, MNr);
        };

        // ---- CSR ----
        zero_i32_kernel<<<(Nn + 255) / 256, 256, 0, stream>>>(deg, Nn);
        hist_kernel<<<gE, 256, 0, stream>>>(edge_index, E, deg);
        scan_kernel<<<1, 1024, 0, stream>>>(deg, rowstart, cursor, Nn);
        scatter_kernel<<<gE, 256, 0, stream>>>(edge_index, E, cursor, eidx);

        // ---- weight transposes (bf16) ----
        cvt_t_bf16_kernel<<<dim3(HID / 32, DF / 32), 256, 0, stream>>>(gat1_wl, w1lT, DF, HID);
        cvt_t_bf16_kernel<<<dim3(HID / 32, DF / 32), 256, 0, stream>>>(gat1_wr, w1rT, DF, HID);
        cvt_t_bf16_kernel<<<dim3(HID / 32, HID / 32), 256, 0, stream>>>(gat2_wl, w2lT, HID, HID);
        cvt_t_bf16_kernel<<<dim3(HID / 32, HID / 32), 256, 0, stream>>>(gat2_wr, w2rT, HID, HID);

        // ---- 2-hop frontier of target_idx ----
        zero_i32_kernel<<<(2 * Nn + 8 + 255) / 256, 256, 0, stream>>>(fbuf, 2 * Nn + 8);
        frontier0_kernel<<<(L + 3) / 4, 256, 0, stream>>>(
            target_idx, L, rowstart, eidx, edge_index, E, f1);
        compact_kernel<<<(Nn + 255) / 256, 256, 0, stream>>>(f1, map1, list1, cnt1, Nn);
        frontier1_kernel<<<cap1 / 4, 256, 0, stream>>>(
            list1, cnt1, rowstart, eidx, edge_index, E, f2);
        compact_kernel<<<(Nn + 255) / 256, 256, 0, stream>>>(f2, map2, list2, cnt2, Nn);

        // ---- gather node features (compact, bf16) ----
        gather_cvt_kernel<<<Nn, 256, 0, stream>>>(node_features, nf2c, list2, cnt2, DF);
        gather_cvt_kernel<<<cap1, 256, 0, stream>>>(node_features, nf1c, list1, cnt1, DF);

        // ---- GAT layer 1 (NH=4) over frontier ----
        gemm_bf16_kernel<0,1><<<8 * gMn2, 256, 0, stream>>>(
            nf2c, w1lT, gat1_bl, xlc, Nn, HID, DF, 8, cnt2);
        gemm_bf16_kernel<0,1><<<8 * gMn1, 256, 0, stream>>>(
            nf1c, w1rT, gat1_br, xrc, cap1, HID, DF, 8, cnt1);
        gat_wave_idx_kernel<4,1,1,0><<<cap1 / 4, 256, 0, stream>>>(
            xlc, xrc, gat1_att, edge_index, rowstart, eidx, map2, list1, cnt1, 0,
            gat1_bias, x1c, E);

        // ---- GAT layer 2 (NH=1) over targets ----
        gemm_bf16_kernel<0,1><<<8 * gMn1, 256, 0, stream>>>(
            x1c, w2lT, gat2_bl, xl2c, cap1, HID, HID, 8, cnt1);
        gemm_bf16_kernel<0,1><<<8 * gMn1, 256, 0, stream>>>(
            x1c, w2rT, gat2_br, xr2c, cap1, HID, HID, 8, cnt1);
        gat_wave_idx_kernel<1,0,0,1><<<(L + 3) / 4, 256, 0, stream>>>(
            xl2c, xr2c, gat2_att, edge_index, rowstart, eidx, map1, target_idx,
            nullptr, L, gat2_bias, x2c, E);

        // ---- cross-attention (1 kv token => softmax==1; q,k proj dead) ----
        gemm_sk8(img_feat, xa_in_w + (size_t)2 * HID * HID, xa_in_b + 2 * HID, vproj, B, HID, HID, 0);
        gemm_sk8(vproj, xa_out_w, xa_out_b, attnb, B, HID, HID, 0);
        ln_cross_kernel<<<R, 256, 0, stream>>>(x2c, attnb, xl_n1_g, xl_n1_b, srcbuf, L);

        // ---- xl FF block ----
        gemm_sk4(srcbuf, xl_l1_w, xl_l1_b, h1buf, R, FFD, HID, 1);
        gemm_sk8_ln(h1buf, xl_l2_w, xl_l2_b, srcbuf, xl_n2_g, xl_n2_b, FFD);

        // ---- 2 encoder layers ----
        for (int i = 0; i < 2; ++i) {
            gemm_sk4(srcbuf, enc_in_w + (size_t)i * 3 * HID * HID, enc_in_b + i * 3 * HID,
                     qkvbuf, R, 3 * HID, HID, 0);
            self_attn_kernel<<<B * 4, 256, 0, stream>>>(qkvbuf, ffbuf, L);
            gemm_sk8_ln(ffbuf, enc_out_w + (size_t)i * HID * HID, enc_out_b + i * HID,
                        srcbuf, enc_n1_g + i * HID, enc_n1_b + i * HID, HID);
            gemm_sk4(srcbuf, enc_l1_w + (size_t)i * FFD * HID, enc_l1_b + i * FFD,
                     h1buf, R, FFD, HID, 1);
            gemm_sk8_ln(h1buf, enc_l2_w + (size_t)i * HID * FFD, enc_l2_b + i * HID,
                        srcbuf, enc_n2_g + i * HID, enc_n2_b + i * HID, FFD);
        }

        // ---- classifier ----
        cls_kernel<<<(R + 3) / 4, 256, 0, stream>>>(srcbuf, cls_w, cls_b, (float*)d_out, R);
    }
}

// Round 2
// 621.670 us; speedup vs baseline: 1.1206x; 1.0404x over previous
//
#include <hip/hip_runtime.h>
#include <hip/hip_bf16.h>

typedef __bf16 bf16;
typedef bf16 bf16x8 __attribute__((ext_vector_type(8)));
typedef bf16 bf16x4 __attribute__((ext_vector_type(4)));
typedef float f32x4 __attribute__((ext_vector_type(4)));

#define HID 1024
#define FFD 2048

typedef __attribute__((address_space(3))) void lds_void;
typedef const __attribute__((address_space(1))) void gm_void;

__device__ __forceinline__ void gload_lds16(const bf16* g, bf16* l)
{
    __builtin_amdgcn_global_load_lds((gm_void*)g, (lds_void*)l, 16, 0, 0);
}

// ---------------------------------------------------------------------------
// Batched fp32->bf16 convert. Each block = 1024 floats. Entries sorted by b0.
// All entry sizes are multiples of 1024 floats.
// ---------------------------------------------------------------------------
struct CvtEnt { const float* src; bf16* dst; int b0; };
struct CvtArgs { CvtEnt e[14]; int n; };

__global__ __launch_bounds__(256) void batch_cvt_kernel(CvtArgs a)
{
    int k = 0;
    while (k + 1 < a.n && (int)blockIdx.x >= a.e[k + 1].b0) ++k;
    const long i = ((long)((int)blockIdx.x - a.e[k].b0) * 256 + threadIdx.x) * 4;
    float4 f = *(const float4*)&a.e[k].src[i];
    bf16x4 v = {(bf16)f.x, (bf16)f.y, (bf16)f.z, (bf16)f.w};
    *(bf16x4*)&a.e[k].dst[i] = v;
}

// ---------------------------------------------------------------------------
// Batched fused fp32->bf16 transpose: in fp32 (R,C) -> out bf16 (C,R).
// blocks per entry = (C/32)*(R/32). Entries sorted by b0.
// ---------------------------------------------------------------------------
struct CvtTEnt { const float* src; bf16* dst; int R, C, b0; };
struct CvtTArgs { CvtTEnt e[4]; int n; };

__global__ __launch_bounds__(256) void batch_cvt_t_kernel(CvtTArgs a)
{
    __shared__ bf16 tile[32][33];
    int k = 0;
    while (k + 1 < a.n && (int)blockIdx.x >= a.e[k + 1].b0) ++k;
    const CvtTEnt en = a.e[k];
    const int lb = (int)blockIdx.x - en.b0;
    const int CB = en.C >> 5;
    const int c0 = (lb % CB) * 32, r0 = (lb / CB) * 32;
    const int tx = threadIdx.x & 31, ty = threadIdx.x >> 5;
#pragma unroll
    for (int i = ty; i < 32; i += 8)
        tile[i][tx] = (bf16)en.src[(long)(r0 + i) * en.C + c0 + tx];
    __syncthreads();
#pragma unroll
    for (int i = ty; i < 32; i += 8)
        en.dst[(long)(c0 + i) * en.R + r0 + tx] = tile[tx][i];
}

// ---------------------------------------------------------------------------
// bf16 GEMM body: C(M,N) = A(M,K) @ Bt(N,K)^T (+bias). 128x128 tile,
// m97-style LDS + async global_load_lds (16B). Optional device row count.
// ---------------------------------------------------------------------------
struct GemmDesc {
    const bf16* A; const bf16* B; const float* bias; void* C;
    int M, N, K, NB; const int* cnt; int act, outbf16;
};

__device__ __forceinline__ void gemm_body(const GemmDesc g, int h, int total,
                                          bf16 (*As)[32], bf16 (*Bs)[32])
{
    const int t = (total % 8 == 0) ? ((h & 7) * (total >> 3) + (h >> 3)) : h;
    const int bn = t % g.NB, bm = t / g.NB;
    int Meff = g.cnt ? *g.cnt : g.M;
    if (Meff <= 0) return;
    if (bm * 128 >= Meff) return;

    const int tid  = threadIdx.x;
    const int lane = tid & 63, wave = tid >> 6;
    const int wr   = wave >> 1, wc = wave & 1;

    f32x4 acc[4][4] = {};

    const int srow = wave * 16 + (lane >> 2);
    const int scol = (lane & 3) << 3;
    const long ga0 = (long)min(bm * 128 + srow,      Meff - 1) * g.K + scol;
    const long ga1 = (long)min(bm * 128 + srow + 64, Meff - 1) * g.K + scol;
    const long gb0 = (long)(bn * 128 + srow)      * g.K + scol;
    const long gb1 = (long)(bn * 128 + srow + 64) * g.K + scol;
    bf16* ldsA0 = &As[0][0] + wave * 512;
    bf16* ldsA1 = &As[0][0] + 2048 + wave * 512;
    bf16* ldsB0 = &Bs[0][0] + wave * 512;
    bf16* ldsB1 = &Bs[0][0] + 2048 + wave * 512;

    const int quad = lane >> 4;
    const int mr   = lane & 15;
    const int kf   = quad * 8;

    for (int k0 = 0; k0 < g.K; k0 += 32) {
        gload_lds16(g.A + ga0 + k0, ldsA0);
        gload_lds16(g.A + ga1 + k0, ldsA1);
        gload_lds16(g.B + gb0 + k0, ldsB0);
        gload_lds16(g.B + gb1 + k0, ldsB1);
        __syncthreads();

        bf16x8 af[4], bfr[4];
#pragma unroll
        for (int i = 0; i < 4; ++i) af[i]  = *(const bf16x8*)&As[wr * 64 + i * 16 + mr][kf];
#pragma unroll
        for (int j = 0; j < 4; ++j) bfr[j] = *(const bf16x8*)&Bs[wc * 64 + j * 16 + mr][kf];
#pragma unroll
        for (int i = 0; i < 4; ++i)
#pragma unroll
            for (int j = 0; j < 4; ++j)
                acc[i][j] = __builtin_amdgcn_mfma_f32_16x16x32_bf16(af[i], bfr[j], acc[i][j], 0, 0, 0);
        __syncthreads();
    }

    const int crow = quad * 4;
#pragma unroll
    for (int i = 0; i < 4; ++i) {
#pragma unroll
        for (int j = 0; j < 4; ++j) {
            const int   col = bn * 128 + wc * 64 + j * 16 + mr;
            const float bv  = g.bias[col];
#pragma unroll
            for (int r = 0; r < 4; ++r) {
                const int row = bm * 128 + wr * 64 + i * 16 + crow + r;
                if (row < Meff) {
                    float v = acc[i][j][r] + bv;
                    if (g.act) v = fmaxf(v, 0.f);
                    if (g.outbf16) ((bf16*)g.C)[(long)row * g.N + col] = (bf16)v;
                    else           ((float*)g.C)[(long)row * g.N + col] = v;
                }
            }
        }
    }
}

__global__ __launch_bounds__(256) void gemm_one_kernel(GemmDesc g)
{
    __shared__ bf16 As[128][32];
    __shared__ bf16 Bs[128][32];
    gemm_body(g, blockIdx.x, gridDim.x, As, Bs);
}

__global__ __launch_bounds__(256) void gemm_dual_kernel(GemmDesc g0, int n0,
                                                        GemmDesc g1, int n1)
{
    __shared__ bf16 As[128][32];
    __shared__ bf16 Bs[128][32];
    if ((int)blockIdx.x < n0) gemm_body(g0, blockIdx.x, n0, As, Bs);
    else                      gemm_body(g1, (int)blockIdx.x - n0, n1, As, Bs);
}

// ---------------------------------------------------------------------------
// bf16 split-K GEMM: fp32 partials to part. grid (N/128, ceil(M/128), KS)
// ---------------------------------------------------------------------------
template <int KS>
__global__ __launch_bounds__(256) void gemm_bsk_kernel(
    const bf16* __restrict__ A, const bf16* __restrict__ B,
    float* __restrict__ part, int M, int N, int K)
{
    const int bn = blockIdx.x, bm = blockIdx.y, kz = blockIdx.z;
    const int tid  = threadIdx.x;
    const int lane = tid & 63, wave = tid >> 6;
    const int wr   = wave >> 1, wc = wave & 1;

    __shared__ bf16 As[128][32];
    __shared__ bf16 Bs[128][32];

    f32x4 acc[4][4] = {};

    const int srow = wave * 16 + (lane >> 2);
    const int scol = (lane & 3) << 3;
    const long ga0 = (long)min(bm * 128 + srow,      M - 1) * K + scol;
    const long ga1 = (long)min(bm * 128 + srow + 64, M - 1) * K + scol;
    const long gb0 = (long)(bn * 128 + srow)      * K + scol;
    const long gb1 = (long)(bn * 128 + srow + 64) * K + scol;
    bf16* ldsA0 = &As[0][0] + wave * 512;
    bf16* ldsA1 = &As[0][0] + 2048 + wave * 512;
    bf16* ldsB0 = &Bs[0][0] + wave * 512;
    bf16* ldsB1 = &Bs[0][0] + 2048 + wave * 512;

    const int quad = lane >> 4;
    const int mr   = lane & 15;
    const int kf   = quad * 8;

    const int Kc = K / KS, kbeg = kz * Kc, kend = kbeg + Kc;
    for (int k0 = kbeg; k0 < kend; k0 += 32) {
        gload_lds16(A + ga0 + k0, ldsA0);
        gload_lds16(A + ga1 + k0, ldsA1);
        gload_lds16(B + gb0 + k0, ldsB0);
        gload_lds16(B + gb1 + k0, ldsB1);
        __syncthreads();

        bf16x8 af[4], bfr[4];
#pragma unroll
        for (int i = 0; i < 4; ++i) af[i]  = *(const bf16x8*)&As[wr * 64 + i * 16 + mr][kf];
#pragma unroll
        for (int j = 0; j < 4; ++j) bfr[j] = *(const bf16x8*)&Bs[wc * 64 + j * 16 + mr][kf];
#pragma unroll
        for (int i = 0; i < 4; ++i)
#pragma unroll
            for (int j = 0; j < 4; ++j)
                acc[i][j] = __builtin_amdgcn_mfma_f32_16x16x32_bf16(af[i], bfr[j], acc[i][j], 0, 0, 0);
        __syncthreads();
    }

    float* dst = part + (size_t)kz * M * N;
    const int crow = quad * 4;
#pragma unroll
    for (int i = 0; i < 4; ++i) {
#pragma unroll
        for (int j = 0; j < 4; ++j) {
            const int col = bn * 128 + wc * 64 + j * 16 + mr;
#pragma unroll
            for (int r = 0; r < 4; ++r) {
                const int row = bm * 128 + wr * 64 + i * 16 + crow + r;
                if (row < M) dst[(long)row * N + col] = acc[i][j][r];
            }
        }
    }
}

// reduce KS partials + bias (+relu) -> bf16 C
template <int ACT, int KS>
__global__ __launch_bounds__(256) void sk_reduce_b16_kernel(
    const float* __restrict__ part, const float* __restrict__ bias,
    bf16* __restrict__ C, long MN, int N)
{
    long i = ((long)blockIdx.x * 256 + threadIdx.x) * 4;
    if (i >= MN) return;
    float4 s = *(const float4*)&part[i];
#pragma unroll
    for (int k = 1; k < KS; ++k) {
        float4 p = *(const float4*)&part[(size_t)k * MN + i];
        s.x += p.x; s.y += p.y; s.z += p.z; s.w += p.w;
    }
    const int col = (int)(i % N);
    float4 bv = *(const float4*)&bias[col];
    s.x += bv.x; s.y += bv.y; s.z += bv.z; s.w += bv.w;
    if (ACT) {
        s.x = fmaxf(s.x, 0.f); s.y = fmaxf(s.y, 0.f);
        s.z = fmaxf(s.z, 0.f); s.w = fmaxf(s.w, 0.f);
    }
    bf16x4 v = {(bf16)s.x, (bf16)s.y, (bf16)s.z, (bf16)s.w};
    *(bf16x4*)&C[i] = v;
}

// ---------------------------------------------------------------------------
// LayerNorm core (row = 1024, block = 256, 4 ch/thread) + bf16 mirror out
// ---------------------------------------------------------------------------
__device__ __forceinline__ void ln_finish(float v[4], int c0, const float* g,
                                          const float* beta, float* outrow,
                                          bf16* outb)
{
    float s1 = v[0] + v[1] + v[2] + v[3];
    float s2 = v[0] * v[0] + v[1] * v[1] + v[2] * v[2] + v[3] * v[3];
    __shared__ float red[8];
    for (int o = 32; o; o >>= 1) { s1 += __shfl_down(s1, o); s2 += __shfl_down(s2, o); }
    const int wave = threadIdx.x >> 6, lane = threadIdx.x & 63;
    if (lane == 0) { red[wave] = s1; red[4 + wave] = s2; }
    __syncthreads();
    if (threadIdx.x == 0) {
        red[0] += red[1] + red[2] + red[3];
        red[4] += red[5] + red[6] + red[7];
    }
    __syncthreads();
    const float mean = red[0] * (1.f / HID);
    const float var  = fmaxf(red[4] * (1.f / HID) - mean * mean, 0.f);
    const float rstd = rsqrtf(var + 1e-5f);
#pragma unroll
    for (int k = 0; k < 4; ++k) {
        int c = c0 + k;
        float o = (v[k] - mean) * rstd * g[c] + beta[c];
        outrow[c] = o;
        outb[c] = (bf16)o;
    }
}

// fused: reduce KS partials + bias + residual(srcio) -> LN -> srcio + bf16
template <int KS>
__global__ __launch_bounds__(256) void sk_reduce_ln_kernel(
    const float* __restrict__ part, const float* __restrict__ bias,
    float* __restrict__ srcio, bf16* __restrict__ srcb,
    const float* __restrict__ g, const float* __restrict__ beta, long MN)
{
    const long row = blockIdx.x;
    const int c0 = threadIdx.x * 4;
    const long base = row * HID + c0;
    float4 s = *(const float4*)&part[base];
#pragma unroll
    for (int k = 1; k < KS; ++k) {
        float4 p = *(const float4*)&part[(size_t)k * MN + base];
        s.x += p.x; s.y += p.y; s.z += p.z; s.w += p.w;
    }
    float4 bv = *(const float4*)&bias[c0];
    float4 rv = *(const float4*)&srcio[base];
    float v[4] = {s.x + bv.x + rv.x, s.y + bv.y + rv.y,
                  s.z + bv.z + rv.z, s.w + bv.w + rv.w};
    ln_finish(v, c0, g, beta, srcio + row * HID, srcb + row * HID);
}

// ---------------------------------------------------------------------------
// Frontier: zero flags/counters + build concat bias for GAT2
// ---------------------------------------------------------------------------
__global__ void zero_prep_kernel(int* __restrict__ zp, int Z,
                                 const float* __restrict__ bl,
                                 const float* __restrict__ br,
                                 float* __restrict__ bias2)
{
    int i = blockIdx.x * 256 + threadIdx.x;
    if (i < Z) zp[i] = 0;
    int j = i - Z;
    if (j >= 0 && j < HID) bias2[j] = bl[j];
    else if (j >= HID && j < 2 * HID) bias2[j] = br[j - HID];
}

// pass over edges: collect srcs of edges into targets; mark f1
__global__ __launch_bounds__(256) void pass0_kernel(
    const int* __restrict__ ei, int E, const int* __restrict__ tgt, int L,
    int* __restrict__ cntE0, int* __restrict__ srcs0, int* __restrict__ f1)
{
    __shared__ int ts[16];
    if ((int)threadIdx.x < L) ts[threadIdx.x] = tgt[threadIdx.x];
    __syncthreads();
    if (blockIdx.x == 0 && (int)threadIdx.x < L) f1[ts[threadIdx.x]] = 1;
    int e = blockIdx.x * 256 + threadIdx.x;
    if (e >= E) return;
    int d = ei[e];
    int c = -1;
    for (int l = 0; l < L; ++l) if (ts[l] == d) { c = l; break; }
    if (c < 0) return;
    int s = atomicAdd(&cntE0[c], 1);
    if (s < 128) { int sr = ei[E + e]; srcs0[c * 128 + s] = sr; f1[sr] = 1; }
}

// pass over edges: collect srcs of edges into f1 nodes; mark f2
__global__ __launch_bounds__(256) void pass1_kernel(
    const int* __restrict__ ei, int E, const int* __restrict__ f1,
    const int* __restrict__ map1, int* __restrict__ cntE1,
    int* __restrict__ srcs1, int* __restrict__ f2)
{
    int e = blockIdx.x * 256 + threadIdx.x;
    if (e >= E) return;
    int d = ei[e];
    if (!f1[d]) return;
    int c = map1[d];
    int s = atomicAdd(&cntE1[c], 1);
    if (s < 128) { int sr = ei[E + e]; srcs1[c * 128 + s] = sr; f2[sr] = 1; }
}

// flags -> compact list + node->compact map
__global__ __launch_bounds__(256) void compact_kernel(
    const int* __restrict__ flags, int* __restrict__ map, int* __restrict__ list,
    int* __restrict__ cnt, int n)
{
    int i = blockIdx.x * 256 + threadIdx.x;
    if (i < n && flags[i]) {
        int p = atomicAdd(cnt, 1);
        list[p] = i;
        map[i] = p;
    }
}

// dual gather: fp32 rows by list -> bf16 compact rows (grid-stride blocks)
__global__ __launch_bounds__(256) void gather2_kernel(
    const float* __restrict__ nf,
    bf16* __restrict__ nf2c, const int* __restrict__ list2, const int* __restrict__ cnt2,
    bf16* __restrict__ nf1c, const int* __restrict__ list1, const int* __restrict__ cnt1,
    int DF)
{
    int bid = blockIdx.x;
    const int* list; int cnt, stride; bf16* dst;
    if (bid < 2048) { list = list2; cnt = *cnt2; dst = nf2c; stride = 2048; }
    else { bid -= 2048; list = list1; cnt = *cnt1; dst = nf1c; stride = 512; }
    for (int r = bid; r < cnt; r += stride) {
        const long i = (long)list[r] * DF;
        const long o = (long)r * DF;
        for (int c = threadIdx.x * 4; c < DF; c += 1024) {
            float4 f = *(const float4*)&nf[i + c];
            bf16x4 v = {(bf16)f.x, (bf16)f.y, (bf16)f.z, (bf16)f.w};
            *(bf16x4*)&dst[o + c] = v;
        }
    }
}

// ---------------------------------------------------------------------------
// Wave-per-node GATv2, layer 1 (NH=4): nodes = list1 (cnt1), edges from slot
// array srcs1[w*128..], src rows via map2 into xlc; xr row = w; out bf16.
// ---------------------------------------------------------------------------
__global__ __launch_bounds__(256) void gat_wave1_kernel(
    const bf16* __restrict__ xl, const bf16* __restrict__ xr,
    const float* __restrict__ att, const int* __restrict__ srcs,
    const int* __restrict__ cntE, const int* __restrict__ srcmap,
    const int* __restrict__ cntp, const float* __restrict__ bias,
    bf16* __restrict__ outp)
{
    const int wave = threadIdx.x >> 6, lane = threadIdx.x & 63;
    const int w = blockIdx.x * 4 + wave;
    if (w >= *cntp) return;
    int deg = min(cntE[w], 128);
    const int base = w * 128;
    int my_src = srcmap[srcs[base + min(lane, deg - 1)]];
    int my_src2 = 0;
    if (deg > 64) my_src2 = srcmap[srcs[base + 64 + min(lane, deg - 65)]];

    const int c0 = lane * 16;
    float xrf[16], av[16];
    {
        bf16x8 r0 = *(const bf16x8*)&xr[(long)w * HID + c0];
        bf16x8 r1 = *(const bf16x8*)&xr[(long)w * HID + c0 + 8];
#pragma unroll
        for (int t = 0; t < 8; ++t) { xrf[t] = (float)r0[t]; xrf[8 + t] = (float)r1[t]; }
        float4 t0 = *(const float4*)&att[c0],     t1 = *(const float4*)&att[c0 + 4];
        float4 t2 = *(const float4*)&att[c0 + 8], t3 = *(const float4*)&att[c0 + 12];
        av[0]=t0.x; av[1]=t0.y; av[2]=t0.z;  av[3]=t0.w;
        av[4]=t1.x; av[5]=t1.y; av[6]=t1.z;  av[7]=t1.w;
        av[8]=t2.x; av[9]=t2.y; av[10]=t2.z; av[11]=t2.w;
        av[12]=t3.x; av[13]=t3.y; av[14]=t3.z; av[15]=t3.w;
    }

    float m = -1e30f, s = 0.f;
    float acc[16];
#pragma unroll
    for (int t = 0; t < 16; ++t) acc[t] = 0.f;

    int sj = __shfl(my_src, 0);
    bf16x8 na0 = *(const bf16x8*)&xl[(long)sj * HID + c0];
    bf16x8 na1 = *(const bf16x8*)&xl[(long)sj * HID + c0 + 8];

    for (int j = 0; j < deg; ++j) {
        bf16x8 x0 = na0, x1 = na1;
        if (j + 1 < deg) {
            int msrc = (j + 1 < 64) ? my_src : my_src2;
            int sn = __shfl(msrc, (j + 1) & 63);
            na0 = *(const bf16x8*)&xl[(long)sn * HID + c0];
            na1 = *(const bf16x8*)&xl[(long)sn * HID + c0 + 8];
        }
        float xf[16];
#pragma unroll
        for (int t = 0; t < 8; ++t) { xf[t] = (float)x0[t]; xf[8 + t] = (float)x1[t]; }
        float partial = 0.f;
#pragma unroll
        for (int t = 0; t < 16; ++t) {
            float v = xf[t] + xrf[t];
            v = v > 0.f ? v : 0.2f * v;
            partial += v * av[t];
        }
#pragma unroll
        for (int o = 1; o < 16; o <<= 1) partial += __shfl_xor(partial, o);
        float mn = fmaxf(m, partial);
        float f = __expf(m - mn);
        float p = __expf(partial - mn);
        s = s * f + p;
#pragma unroll
        for (int t = 0; t < 16; ++t) acc[t] = acc[t] * f + p * xf[t];
        m = mn;
    }

    const float dinv = 1.f / (s + 1e-16f);
    float bv[16];
    {
        float4 t0 = *(const float4*)&bias[c0],     t1 = *(const float4*)&bias[c0 + 4];
        float4 t2 = *(const float4*)&bias[c0 + 8], t3 = *(const float4*)&bias[c0 + 12];
        bv[0]=t0.x; bv[1]=t0.y; bv[2]=t0.z;  bv[3]=t0.w;
        bv[4]=t1.x; bv[5]=t1.y; bv[6]=t1.z;  bv[7]=t1.w;
        bv[8]=t2.x; bv[9]=t2.y; bv[10]=t2.z; bv[11]=t2.w;
        bv[12]=t3.x; bv[13]=t3.y; bv[14]=t3.z; bv[15]=t3.w;
    }
    bf16x8 w0, w1;
#pragma unroll
    for (int t = 0; t < 16; ++t) {
        float v = acc[t] * dinv + bv[t];
        v = v > 0.f ? v : 0.2f * v;   // leaky relu between layers
        if (t < 8) w0[t] = (bf16)v; else w1[t - 8] = (bf16)v;
    }
    *(bf16x8*)&outp[(long)w * HID + c0] = w0;
    *(bf16x8*)&outp[(long)w * HID + c0 + 8] = w1;
}

// ---------------------------------------------------------------------------
// Wave-per-target GATv2, layer 2 (NH=1): x12 holds [xl | xr] stride 2048,
// rows indexed by map1. out fp32 row w.
// ---------------------------------------------------------------------------
__global__ __launch_bounds__(256) void gat_wave2_kernel(
    const bf16* __restrict__ x12, const float* __restrict__ att,
    const int* __restrict__ tgt, int L, const int* __restrict__ srcs,
    const int* __restrict__ cntE, const int* __restrict__ map1,
    const float* __restrict__ bias, float* __restrict__ outp)
{
    const int wave = threadIdx.x >> 6, lane = threadIdx.x & 63;
    const int w = blockIdx.x * 4 + wave;
    if (w >= L) return;
    const int n = tgt[w];
    int c = 0;
    for (int l = 0; l < L; ++l) if (tgt[l] == n) { c = l; break; }
    int deg = min(cntE[c], 128);
    const int base = c * 128;
    int my_src = map1[srcs[base + min(lane, deg - 1)]];
    int my_src2 = 0;
    if (deg > 64) my_src2 = map1[srcs[base + 64 + min(lane, deg - 65)]];

    const int c0 = lane * 16;
    const long LD = 2 * HID;
    float xrf[16], av[16];
    {
        const long xrr = (long)map1[n] * LD + HID + c0;
        bf16x8 r0 = *(const bf16x8*)&x12[xrr];
        bf16x8 r1 = *(const bf16x8*)&x12[xrr + 8];
#pragma unroll
        for (int t = 0; t < 8; ++t) { xrf[t] = (float)r0[t]; xrf[8 + t] = (float)r1[t]; }
        float4 t0 = *(const float4*)&att[c0],     t1 = *(const float4*)&att[c0 + 4];
        float4 t2 = *(const float4*)&att[c0 + 8], t3 = *(const float4*)&att[c0 + 12];
        av[0]=t0.x; av[1]=t0.y; av[2]=t0.z;  av[3]=t0.w;
        av[4]=t1.x; av[5]=t1.y; av[6]=t1.z;  av[7]=t1.w;
        av[8]=t2.x; av[9]=t2.y; av[10]=t2.z; av[11]=t2.w;
        av[12]=t3.x; av[13]=t3.y; av[14]=t3.z; av[15]=t3.w;
    }

    float m = -1e30f, s = 0.f;
    float acc[16];
#pragma unroll
    for (int t = 0; t < 16; ++t) acc[t] = 0.f;

    int sj = __shfl(my_src, 0);
    bf16x8 na0 = *(const bf16x8*)&x12[(long)sj * LD + c0];
    bf16x8 na1 = *(const bf16x8*)&x12[(long)sj * LD + c0 + 8];

    for (int j = 0; j < deg; ++j) {
        bf16x8 x0 = na0, x1 = na1;
        if (j + 1 < deg) {
            int msrc = (j + 1 < 64) ? my_src : my_src2;
            int sn = __shfl(msrc, (j + 1) & 63);
            na0 = *(const bf16x8*)&x12[(long)sn * LD + c0];
            na1 = *(const bf16x8*)&x12[(long)sn * LD + c0 + 8];
        }
        float xf[16];
#pragma unroll
        for (int t = 0; t < 8; ++t) { xf[t] = (float)x0[t]; xf[8 + t] = (float)x1[t]; }
        float partial = 0.f;
#pragma unroll
        for (int t = 0; t < 16; ++t) {
            float v = xf[t] + xrf[t];
            v = v > 0.f ? v : 0.2f * v;
            partial += v * av[t];
        }
#pragma unroll
        for (int o = 1; o < 64; o <<= 1) partial += __shfl_xor(partial, o);
        float mn = fmaxf(m, partial);
        float f = __expf(m - mn);
        float p = __expf(partial - mn);
        s = s * f + p;
#pragma unroll
        for (int t = 0; t < 16; ++t) acc[t] = acc[t] * f + p * xf[t];
        m = mn;
    }

    const float dinv = 1.f / (s + 1e-16f);
    float* op = outp + (long)w * HID + c0;
#pragma unroll
    for (int t = 0; t < 4; ++t) {
        float4 b4 = *(const float4*)&bias[c0 + t * 4];
        float4 wv = {acc[t*4] * dinv + b4.x, acc[t*4+1] * dinv + b4.y,
                     acc[t*4+2] * dinv + b4.z, acc[t*4+3] * dinv + b4.w};
        *(float4*)&op[t * 4] = wv;
    }
}

// ---------------------------------------------------------------------------
// LayerNorm after cross-attn: x2c row l + attnb row b -> srcbuf + bf16 mirror
// ---------------------------------------------------------------------------
__global__ __launch_bounds__(256) void ln_cross_kernel(
    const float* __restrict__ x2c, const float* __restrict__ attnb,
    const float* __restrict__ g, const float* __restrict__ beta,
    float* __restrict__ out, bf16* __restrict__ outb, int L)
{
    const int row = blockIdx.x;
    const int b = row / L, l = row - b * L;
    const int c0 = threadIdx.x * 4;
    float v[4];
#pragma unroll
    for (int k = 0; k < 4; ++k)
        v[k] = x2c[(long)l * HID + c0 + k] + attnb[(long)b * HID + c0 + k];
    ln_finish(v, c0, g, beta, out + (long)row * HID, outb + (long)row * HID);
}

// ---------------------------------------------------------------------------
// Self-attention core, reading split-K qkv partials directly (+bias),
// writing bf16 for the out-projection. One block per (batch, head).
// ---------------------------------------------------------------------------
template <int KS>
__global__ __launch_bounds__(256) void self_attn_sk_kernel(
    const float* __restrict__ part, const float* __restrict__ bias,
    bf16* __restrict__ out, int L, int R)
{
    const int b = blockIdx.x >> 2, h = blockIdx.x & 3;
    const int tid = threadIdx.x;
    __shared__ float q[16][256], kk[16][256], vv[16][256];
    __shared__ float sc[16][16];
    const size_t PS = (size_t)R * 3 * HID;
    for (int i = tid; i < L * 256; i += 256) {
        const int l = i >> 8, d = i & 255;
        const long rb = (long)(b * L + l) * 3 * HID + h * 256 + d;
        float sq = part[rb], sk = part[rb + HID], sv = part[rb + 2 * HID];
#pragma unroll
        for (int k = 1; k < KS; ++k) {
            sq += part[k * PS + rb];
            sk += part[k * PS + rb + HID];
            sv += part[k * PS + rb + 2 * HID];
        }
        q[l][d]  = sq + bias[h * 256 + d];
        kk[l][d] = sk + bias[HID + h * 256 + d];
        vv[l][d] = sv + bias[2 * HID + h * 256 + d];
    }
    __syncthreads();
    if (tid < L * L) {
        const int l1 = tid / L, l2 = tid - l1 * L;
        float s = 0.f;
        for (int d = 0; d < 256; ++d) s += q[l1][d] * kk[l2][d];
        sc[l1][l2] = s * 0.0625f;
    }
    __syncthreads();
    if (tid < L) {
        float mx = -1e30f;
        for (int j = 0; j < L; ++j) mx = fmaxf(mx, sc[tid][j]);
        float ssum = 0.f;
        for (int j = 0; j < L; ++j) { float e = expf(sc[tid][j] - mx); sc[tid][j] = e; ssum += e; }
        const float inv = 1.f / ssum;
        for (int j = 0; j < L; ++j) sc[tid][j] *= inv;
    }
    __syncthreads();
    for (int l1 = 0; l1 < L; ++l1) {
        float a = 0.f;
        for (int l2 = 0; l2 < L; ++l2) a += sc[l1][l2] * vv[l2][tid];
        out[(long)(b * L + l1) * HID + h * 256 + tid] = (bf16)a;
    }
}

// ---------------------------------------------------------------------------
__global__ __launch_bounds__(256) void cls_kernel(
    const float* __restrict__ src, const float* __restrict__ w,
    const float* __restrict__ b, float* __restrict__ out, int rows)
{
    const int row = blockIdx.x * 4 + (threadIdx.x >> 6);
    const int lane = threadIdx.x & 63;
    if (row >= rows) return;
    float s = 0.f;
    for (int c = lane; c < HID; c += 64) s += src[(long)row * HID + c] * w[c];
    for (int o = 32; o; o >>= 1) s += __shfl_down(s, o);
    if (lane == 0) out[row] = s + b[0];
}

// ---------------------------------------------------------------------------
extern "C" void kernel_launch(void* const* d_in, const int* in_sizes, int n_in,
                              void* d_out, int out_size, void* d_ws, size_t ws_size,
                              hipStream_t stream)
{
    const float* img_feat      = (const float*)d_in[0];
    const float* node_features = (const float*)d_in[1];
    const int*   edge_index    = (const int*)d_in[2];
    const int*   target_idx    = (const int*)d_in[3];
    const float* gat1_wl  = (const float*)d_in[4];
    const float* gat1_bl  = (const float*)d_in[5];
    const float* gat1_wr  = (const float*)d_in[6];
    const float* gat1_br  = (const float*)d_in[7];
    const float* gat1_att = (const float*)d_in[8];
    const float* gat1_bias= (const float*)d_in[9];
    const float* gat2_wl  = (const float*)d_in[10];
    const float* gat2_bl  = (const float*)d_in[11];
    const float* gat2_wr  = (const float*)d_in[12];
    const float* gat2_br  = (const float*)d_in[13];
    const float* gat2_att = (const float*)d_in[14];
    const float* gat2_bias= (const float*)d_in[15];
    const float* xa_in_w  = (const float*)d_in[16];
    const float* xa_in_b  = (const float*)d_in[17];
    const float* xa_out_w = (const float*)d_in[18];
    const float* xa_out_b = (const float*)d_in[19];
    const float* xl_l1_w  = (const float*)d_in[20];
    const float* xl_l1_b  = (const float*)d_in[21];
    const float* xl_l2_w  = (const float*)d_in[22];
    const float* xl_l2_b  = (const float*)d_in[23];
    const float* xl_n1_g  = (const float*)d_in[24];
    const float* xl_n1_b  = (const float*)d_in[25];
    const float* xl_n2_g  = (const float*)d_in[26];
    const float* xl_n2_b  = (const float*)d_in[27];
    const float* enc_in_w = (const float*)d_in[28];
    const float* enc_in_b = (const float*)d_in[29];
    const float* enc_out_w= (const float*)d_in[30];
    const float* enc_out_b= (const float*)d_in[31];
    const float* enc_l1_w = (const float*)d_in[32];
    const float* enc_l1_b = (const float*)d_in[33];
    const float* enc_l2_w = (const float*)d_in[34];
    const float* enc_l2_b = (const float*)d_in[35];
    const float* enc_n1_g = (const float*)d_in[36];
    const float* enc_n1_b = (const float*)d_in[37];
    const float* enc_n2_g = (const float*)d_in[38];
    const float* enc_n2_b = (const float*)d_in[39];
    const float* cls_w    = (const float*)d_in[40];
    const float* cls_b    = (const float*)d_in[41];

    const int DF = in_sizes[4] / HID;          // 768
    const int Nn = in_sizes[1] / DF;           // 8000
    const int E  = in_sizes[2] / 2;            // 104000
    const int L  = in_sizes[3];                // 14  (<= 16)
    const int B  = in_sizes[0] / HID;          // 32
    const int R  = B * L;                      // 448

    const int cap1 = ((L * 129 + 127) / 128) * 128;   // 1-hop cap (1920)
    const int gMn1 = cap1 / 128;
    const int gMn2 = (Nn + 127) / 128;

    // ---- workspace layout ----
    char* basep = (char*)d_ws;
    size_t off = 0;
    auto alloc = [&](size_t bytes) -> char* {
        char* r = basep + off; off += (bytes + 255) & ~(size_t)255; return r;
    };

    bf16* w1lT = (bf16*)alloc((size_t)DF * HID * 2);
    bf16* w1rT = (bf16*)alloc((size_t)DF * HID * 2);
    bf16* w2T  = (bf16*)alloc((size_t)2 * HID * HID * 2);
    float* bias2 = (float*)alloc((size_t)2 * HID * 4);

    bf16* xa_v_b  = (bf16*)alloc((size_t)HID * HID * 2);
    bf16* xa_o_b  = (bf16*)alloc((size_t)HID * HID * 2);
    bf16* xl1_b   = (bf16*)alloc((size_t)FFD * HID * 2);
    bf16* xl2_b   = (bf16*)alloc((size_t)HID * FFD * 2);
    bf16* ein_b[2], *eout_b[2], *el1_b[2], *el2_b[2];
    for (int i = 0; i < 2; ++i) {
        ein_b[i]  = (bf16*)alloc((size_t)3 * HID * HID * 2);
        eout_b[i] = (bf16*)alloc((size_t)HID * HID * 2);
        el1_b[i]  = (bf16*)alloc((size_t)FFD * HID * 2);
        el2_b[i]  = (bf16*)alloc((size_t)HID * FFD * 2);
    }
    bf16* imgb = (bf16*)alloc((size_t)B * HID * 2);

    int* zbase = (int*)alloc((size_t)(2 * Nn + cap1 + 32) * 4);
    int* f1 = zbase;
    int* f2 = f1 + Nn;
    int* cntE1 = f2 + Nn;
    int* cntE0 = cntE1 + cap1;
    int* cnt1 = cntE0 + 16;
    int* cnt2 = cnt1 + 1;
    const int Z = 2 * Nn + cap1 + 18;

    int* map1  = (int*)alloc((size_t)Nn * 4);
    int* map2  = (int*)alloc((size_t)Nn * 4);
    int* list1 = (int*)alloc((size_t)cap1 * 4);
    int* list2 = (int*)alloc((size_t)Nn * 4);
    int* srcs0 = (int*)alloc((size_t)16 * 128 * 4);
    int* srcs1 = (int*)alloc((size_t)cap1 * 128 * 4);

    bf16* nf2c = (bf16*)alloc((size_t)Nn * DF * 2);
    bf16* nf1c = (bf16*)alloc((size_t)cap1 * DF * 2);
    bf16* xlc  = (bf16*)alloc((size_t)Nn * HID * 2);
    bf16* xrc  = (bf16*)alloc((size_t)cap1 * HID * 2);
    bf16* x1c  = (bf16*)alloc((size_t)cap1 * HID * 2);
    bf16* x12c = (bf16*)alloc((size_t)cap1 * 2 * HID * 2);
    float* x2c = (float*)alloc((size_t)16 * HID * 4);
    bf16* vprojb = (bf16*)alloc((size_t)B * HID * 2);
    float* attnb = (float*)alloc((size_t)B * HID * 4);
    float* srcbuf = (float*)alloc((size_t)R * HID * 4);
    bf16*  srcb16 = (bf16*)alloc((size_t)R * HID * 2);
    bf16*  h1b    = (bf16*)alloc((size_t)R * FFD * 2);
    bf16*  ffb16  = (bf16*)alloc((size_t)R * HID * 2);
    float* skpart = (float*)alloc((size_t)4 * R * 3 * HID * 4);

    const int gE = (E + 255) / 256;
    const long MNr = (long)R * HID;

    // ---- batched weight transposes (GAT) ----
    {
        CvtTArgs ta; ta.n = 4;
        int b0 = 0;
        ta.e[0] = {gat1_wl, w1lT, DF, HID, b0};  b0 += (HID/32)*(DF/32);
        ta.e[1] = {gat1_wr, w1rT, DF, HID, b0};  b0 += (HID/32)*(DF/32);
        ta.e[2] = {gat2_wl, w2T,             HID, HID, b0}; b0 += (HID/32)*(HID/32);
        ta.e[3] = {gat2_wr, w2T + (size_t)HID*HID, HID, HID, b0}; b0 += (HID/32)*(HID/32);
        batch_cvt_t_kernel<<<b0, 256, 0, stream>>>(ta);
    }
    // ---- batched weight/img converts (transformer) ----
    {
        CvtArgs ca; int b0 = 0, k = 0;
        auto add = [&](const float* s, bf16* d, long elems) {
            ca.e[k++] = {s, d, b0}; b0 += (int)(elems / 1024);
        };
        add(img_feat, imgb, (long)B * HID);
        add(xa_in_w + (size_t)2 * HID * HID, xa_v_b, (long)HID * HID);
        add(xa_out_w, xa_o_b, (long)HID * HID);
        add(xl_l1_w, xl1_b, (long)FFD * HID);
        add(xl_l2_w, xl2_b, (long)HID * FFD);
        for (int i = 0; i < 2; ++i) {
            add(enc_in_w  + (size_t)i * 3 * HID * HID, ein_b[i],  (long)3 * HID * HID);
            add(enc_out_w + (size_t)i * HID * HID,     eout_b[i], (long)HID * HID);
            add(enc_l1_w  + (size_t)i * FFD * HID,     el1_b[i],  (long)FFD * HID);
            add(enc_l2_w  + (size_t)i * HID * FFD,     el2_b[i],  (long)HID * FFD);
        }
        ca.n = k;
        batch_cvt_kernel<<<b0, 256, 0, stream>>>(ca);
    }

    // ---- frontier (2-hop of targets), direct edge-slot lists, no CSR ----
    zero_prep_kernel<<<(Z + 2 * HID + 255) / 256, 256, 0, stream>>>(
        zbase, Z, gat2_bl, gat2_br, bias2);
    pass0_kernel<<<gE, 256, 0, stream>>>(edge_index, E, target_idx, L, cntE0, srcs0, f1);
    compact_kernel<<<(Nn + 255) / 256, 256, 0, stream>>>(f1, map1, list1, cnt1, Nn);
    pass1_kernel<<<gE, 256, 0, stream>>>(edge_index, E, f1, map1, cntE1, srcs1, f2);
    compact_kernel<<<(Nn + 255) / 256, 256, 0, stream>>>(f2, map2, list2, cnt2, Nn);

    // ---- gather node features (compact, bf16), both frontiers ----
    gather2_kernel<<<2560, 256, 0, stream>>>(node_features, nf2c, list2, cnt2,
                                             nf1c, list1, cnt1, DF);

    // ---- GAT layer 1: l-proj over list2 + r-proj over list1, one dispatch ----
    {
        GemmDesc gl = {nf2c, w1lT, gat1_bl, xlc, Nn,   HID, DF, 8, cnt2, 0, 1};
        GemmDesc gr = {nf1c, w1rT, gat1_br, xrc, cap1, HID, DF, 8, cnt1, 0, 1};
        int n0 = 8 * gMn2, n1 = 8 * gMn1;
        gemm_dual_kernel<<<n0 + n1, 256, 0, stream>>>(gl, n0, gr, n1);
    }
    gat_wave1_kernel<<<cap1 / 4, 256, 0, stream>>>(
        xlc, xrc, gat1_att, srcs1, cntE1, map2, cnt1, gat1_bias, x1c);

    // ---- GAT layer 2: stacked [l|r] projection (N=2048), one dispatch ----
    {
        GemmDesc g2 = {x1c, w2T, bias2, x12c, cap1, 2 * HID, HID, 16, cnt1, 0, 1};
        gemm_one_kernel<<<16 * gMn1, 256, 0, stream>>>(g2);
    }
    gat_wave2_kernel<<<(L + 3) / 4, 256, 0, stream>>>(
        x12c, gat2_att, target_idx, L, srcs0, cntE0, map1, gat2_bias, x2c);

    // ---- cross-attention (1 kv token => softmax==1; q,k proj dead) ----
    {
        GemmDesc gv = {imgb, xa_v_b, xa_in_b + 2 * HID, vprojb, B, HID, HID, 8, nullptr, 0, 1};
        gemm_one_kernel<<<8, 256, 0, stream>>>(gv);
        GemmDesc go = {vprojb, xa_o_b, xa_out_b, attnb, B, HID, HID, 8, nullptr, 0, 0};
        gemm_one_kernel<<<8, 256, 0, stream>>>(go);
    }
    ln_cross_kernel<<<R, 256, 0, stream>>>(x2c, attnb, xl_n1_g, xl_n1_b, srcbuf, srcb16, L);

    // ---- xl FF block ----
    gemm_bsk_kernel<4><<<dim3(FFD / 128, (R + 127) / 128, 4), 256, 0, stream>>>(
        srcb16, xl1_b, skpart, R, FFD, HID);
    sk_reduce_b16_kernel<1, 4><<<(int)(((long)R * FFD / 4 + 255) / 256), 256, 0, stream>>>(
        skpart, xl_l1_b, h1b, (long)R * FFD, FFD);
    gemm_bsk_kernel<8><<<dim3(HID / 128, (R + 127) / 128, 8), 256, 0, stream>>>(
        h1b, xl2_b, skpart, R, HID, FFD);
    sk_reduce_ln_kernel<8><<<R, 256, 0, stream>>>(
        skpart, xl_l2_b, srcbuf, srcb16, xl_n2_g, xl_n2_b, MNr);

    // ---- 2 encoder layers ----
    for (int i = 0; i < 2; ++i) {
        gemm_bsk_kernel<4><<<dim3(3 * HID / 128, (R + 127) / 128, 4), 256, 0, stream>>>(
            srcb16, ein_b[i], skpart, R, 3 * HID, HID);
        self_attn_sk_kernel<4><<<B * 4, 256, 0, stream>>>(
            skpart, enc_in_b + (size_t)i * 3 * HID, ffb16, L, R);
        gemm_bsk_kernel<4><<<dim3(HID / 128, (R + 127) / 128, 4), 256, 0, stream>>>(
            ffb16, eout_b[i], skpart, R, HID, HID);
        sk_reduce_ln_kernel<4><<<R, 256, 0, stream>>>(
            skpart, enc_out_b + (size_t)i * HID, srcbuf, srcb16,
            enc_n1_g + (size_t)i * HID, enc_n1_b + (size_t)i * HID, MNr);
        gemm_bsk_kernel<4><<<dim3(FFD / 128, (R + 127) / 128, 4), 256, 0, stream>>>(
            srcb16, el1_b[i], skpart, R, FFD, HID);
        sk_reduce_b16_kernel<1, 4><<<(int)(((long)R * FFD / 4 + 255) / 256), 256, 0, stream>>>(
            skpart, enc_l1_b + (size_t)i * FFD, h1b, (long)R * FFD, FFD);
        gemm_bsk_kernel<8><<<dim3(HID / 128, (R + 127) / 128, 8), 256, 0, stream>>>(
            h1b, el2_b[i], skpart, R, HID, FFD);
        sk_reduce_ln_kernel<8><<<R, 256, 0, stream>>>(
            skpart, enc_l2_b + (size_t)i * HID, srcbuf, srcb16,
            enc_n2_g + (size_t)i * HID, enc_n2_b + (size_t)i * HID, MNr);
    }

    // ---- classifier ----
    cls_kernel<<<(R + 3) / 4, 256, 0, stream>>>(srcbuf, cls_w, cls_b, (float*)d_out, R);
}